// Round 3
// baseline (304.225 us; speedup 1.0000x reference)
//
#include <hip/hip_runtime.h>
#include <hip/hip_bf16.h>
#include <math.h>

// SpatialAttention B=8, C_IN=256 (d_v), C_OUT=128 (d_qk), N=4096.
// Round 10: (a) flash: V loaded global->VGPR directly ([c][n] layout IS the
// PV fragment layout); K quad-buffered prefetch-2, P quad-buffered, ONE
// barrier per k-tile with the RACE INVARIANT restored: every LDS buffer's
// DMA-rewrite is >=2 barriers after its last read (r9's 1-barrier WAR raced).
// (b) proj3: epilogues stage D through LDS (dead transpose buffer) and emit
// fully-coalesced int4 global stores instead of 32 scalar u16 scattered
// stores per thread (outT tiled layout is contiguous 2x8KB per block).
//   cvt_w : Wq*log2e, Wk -> fp16; bqs = bq*log2e          (unchanged)
//   flash : S mfma f16, P = 2^(S') unnormalized bf16, PV mfma bf16,
//           divide-by-l epilogue.

#define B_   8
#define CIN  256
#define COUT 128
#define NN   4096

typedef _Float16 half8  __attribute__((ext_vector_type(8)));
typedef short    short8 __attribute__((ext_vector_type(8)));
typedef float    f32x4  __attribute__((ext_vector_type(4)));

#define LOG2E 1.44269504088896340736f

__device__ __forceinline__ unsigned short f2h(float f) {
    union { _Float16 h; unsigned short u; } v; v.h = (_Float16)f;
    return v.u;
}
// packed f32x2 -> bf16x2 in one VALU op (no builtin on gfx950; inline asm)
__device__ __forceinline__ unsigned int cvt_pk_bf16(float lo, float hi) {
    unsigned int r;
    asm("v_cvt_pk_bf16_f32 %0, %1, %2" : "=v"(r) : "v"(lo), "v"(hi));
    return r;
}
// lane^1 exchange on the VALU pipe: DPP quad_perm [1,0,3,2] (ctrl 0xB1)
__device__ __forceinline__ float dpp_xor1(float x) {
    union { float f; int i; } u; u.f = x;
    u.i = __builtin_amdgcn_mov_dpp(u.i, 0xB1, 0xF, 0xF, true);
    return u.f;
}
// async 16B global->LDS; LDS dest = wave-uniform base + lane*16
__device__ __forceinline__ void dma16(void* lds, const void* g) {
    __builtin_amdgcn_global_load_lds(
        (const __attribute__((address_space(1))) unsigned int*)g,
        (__attribute__((address_space(3))) unsigned int*)lds,
        16, 0, 0);
}

// ---- weights: Whq = Wq*log2e (fp16), Whk = Wk (fp16); bqs = bq*log2e ----
__global__ __launch_bounds__(256) void cvt_w(const float* __restrict__ Wq,
                                             const float* __restrict__ Wk,
                                             const float* __restrict__ bq,
                                             _Float16* __restrict__ Whq,
                                             _Float16* __restrict__ Whk,
                                             float* __restrict__ bqs) {
    const int bx = blockIdx.x, t = threadIdx.x;
    const int isK = (bx >= 32);
    const float* src = isK ? Wk : Wq;
    _Float16* dst = isK ? Whk : Whq;
    const float scale = isK ? 1.0f : LOG2E;
    const int idx = (bx & 31) * 256 + t;
    float4 v = ((const float4*)src)[idx];
    unsigned long long pk = (unsigned long long)f2h(v.x * scale)
                          | ((unsigned long long)f2h(v.y * scale) << 16)
                          | ((unsigned long long)f2h(v.z * scale) << 32)
                          | ((unsigned long long)f2h(v.w * scale) << 48);
    ((unsigned long long*)dst)[idx] = pk;
    if (bx == 0 && t < COUT) bqs[t] = bq[t] * LOG2E;
}

// ---- projection; Q pass -> outN, K pass -> outT (swizzled tiled) + Vb ----
__global__ __launch_bounds__(256) void proj3(const float* __restrict__ X,     // [B][CIN][NN] fp32
                                             const _Float16* __restrict__ Wh, // [COUT][CIN] fp16
                                             const float* __restrict__ bias,  // [COUT] fp32
                                             _Float16* __restrict__ outN,     // [B][NN][COUT] or null
                                             _Float16* __restrict__ outT,     // tiled K or null
                                             unsigned short* __restrict__ Vb) // [B][CIN][NN] bf16 / null
{
    __shared__ __align__(16) unsigned short T[64 * 264];   // transpose, then output staging
    const int bx = blockIdx.x, b = bx >> 6, n0 = (bx & 63) << 6;
    const int t  = threadIdx.x;
    const int cr = t >> 2;
    const int nch = (t & 3) << 4;

#pragma unroll
    for (int it = 0; it < 4; ++it) {
        const int c = it * 64 + cr;
        const float* src = X + ((size_t)(b * CIN + c) * NN + n0 + nch);
        float v[16];
#pragma unroll
        for (int k = 0; k < 4; ++k) {
            float4 f = *(const float4*)(src + k * 4);
            v[k*4] = f.x; v[k*4+1] = f.y; v[k*4+2] = f.z; v[k*4+3] = f.w;
        }
#pragma unroll
        for (int j = 0; j < 16; ++j) T[(nch + j) * 264 + c] = f2h(v[j]);
        if (Vb) {
            unsigned int o2[8];
#pragma unroll
            for (int j = 0; j < 8; ++j) o2[j] = cvt_pk_bf16(v[2*j], v[2*j+1]);
            unsigned short* dst = Vb + (size_t)(b * CIN + c) * NN + n0 + nch;
            *(int4*)dst = *(int4*)&o2[0];
            *(int4*)(dst + 8) = *(int4*)&o2[4];
        }
    }
    __syncthreads();

    const int w = t >> 6, lane = t & 63, l15 = lane & 15, quad = lane >> 4, q8 = quad * 8;
    half8 a[8];
#pragma unroll
    for (int s = 0; s < 8; ++s)
        a[s] = *(const half8*)&T[(w * 16 + l15) * 264 + s * 32 + q8];
    f32x4 D[8];
#pragma unroll
    for (int og = 0; og < 8; ++og) D[og] = (f32x4){0.f, 0.f, 0.f, 0.f};
#pragma unroll
    for (int s = 0; s < 8; ++s) {
        const _Float16* wp = Wh + (size_t)l15 * CIN + s * 32 + q8;
#pragma unroll
        for (int og = 0; og < 8; ++og) {
            half8 wf = *(const half8*)(wp + og * 16 * CIN);
            D[og] = __builtin_amdgcn_mfma_f32_16x16x32_f16(a[s], wf, D[og], 0, 0, 0);
        }
    }
    // T's a[] fragments are fully consumed by the MFMA loop above in every
    // wave, so after this barrier T is dead -> reuse as output staging.
    __syncthreads();

    if (outT) {
        // stage into the tiled-swizzled layout: 2 local tiles x 4096 halfs,
        // tile-local addr = (c*32 + ((m + 4*(c&7)) & 31))*8 + (o&7)
        const int nrow = w * 16 + quad * 4;   // local n
#pragma unroll
        for (int og = 0; og < 8; ++og) {
            const int o = og * 16 + l15;
            const float bo = bias[o];
            const int c = o >> 3, j = o & 7;
            const int sw = (c & 7) << 2;
#pragma unroll
            for (int r2 = 0; r2 < 4; ++r2) {
                const int n = nrow + r2;
                const int tl = n >> 5, m = n & 31;
                T[tl * 4096 + (c * 32 + ((m + sw) & 31)) * 8 + j] = f2h(D[og][r2] + bo);
            }
        }
        __syncthreads();
        // dump 16KB contiguous (block owns global tiles n0/32, n0/32+1)
        _Float16* dstk = outT + ((size_t)(b * 128 + (n0 >> 5)) * 4096 + t * 32);
        const unsigned short* srck = T + t * 32;
#pragma unroll
        for (int k = 0; k < 4; ++k)
            ((int4*)dstk)[k] = ((const int4*)srck)[k];
    } else {
        // stage [n][o] fp16, row stride 136 halfs (272B, 16B-aligned rows)
        const int nrow = w * 16 + quad * 4;
#pragma unroll
        for (int og = 0; og < 8; ++og) {
            const int o = og * 16 + l15;
            const float bo = bias[o];
#pragma unroll
            for (int r2 = 0; r2 < 4; ++r2)
                T[(nrow + r2) * 136 + o] = f2h(D[og][r2] + bo);
        }
        __syncthreads();
        const int n = t >> 2, seg = t & 3;
        const unsigned short* srcp = T + n * 136 + seg * 32;
        _Float16* dstp = outN + ((size_t)(b * NN + n0 + n) * COUT + seg * 32);
#pragma unroll
        for (int k = 0; k < 4; ++k)
            ((int4*)dstp)[k] = ((const int4*)srcp)[k];
    }
}

// ---- flash attention: 1 barrier per k-tile, V in registers ----
// Q fp16 [b][4096][128] (pre-scaled by log2e); Ktt fp16 swizzled-tiled;
// V bf16 [b][256][4096]; out fp32 [b][256][4096]
// LDS: K quad 32KB + P quad 20KB + Lsh = 52.3KB
// Race invariant: every LDS buffer's DMA-rewrite is issued >=2 barriers
// after its last reader (K[(kt+2)&3] read pre-B(kt-2), issued post-B(kt-1);
// P[kt&3] read pre-B(kt+1), ds_write-rewritten post-B(kt+3)).
__global__ __launch_bounds__(256, 2) void flash_kernel(const _Float16* __restrict__ Q,
                                                       const _Float16* __restrict__ Ktt,
                                                       const unsigned short* __restrict__ V,
                                                       float* __restrict__ out) {
    __shared__ __align__(16) _Float16       Ksh[4 * 32 * 128];   // 4 x 8KB
    __shared__ __align__(16) unsigned short Psh[4 * 64 * 40];    // 4 x 5KB
    __shared__ __align__(16) float          Lsh[64];

    const int bx   = blockIdx.x;          // 512 = B * 64 q-tiles
    const int b    = bx >> 6;
    const int q0   = (bx & 63) << 6;
    const int t    = threadIdx.x;
    const int w    = t >> 6;
    const int lane = t & 63;
    const int l15  = lane & 15;
    const int quad = lane >> 4;
    const int q8   = quad * 8;

    const _Float16* Qg = Q + (size_t)b * NN * COUT;
    const _Float16* Kb = Ktt + (size_t)b * 128 * 4096;   // 128 tiles x 4096 halfs
    const unsigned short* Vg = V + (size_t)b * CIN * NN;

    // Q fragments: wave w owns S rows q0+w*16 .. +15, resident all kernel
    half8 Qf[4];
    {
        const _Float16* qr = Qg + (size_t)(q0 + w * 16 + l15) * COUT;
#pragma unroll
        for (int s = 0; s < 4; ++s)
            Qf[s] = *(const half8*)(qr + s * 32 + q8);
    }

    f32x4 O[16];   // O[ni*4+cj]: n-block ni (16 n), c = w*64 + cj*16 + l15
#pragma unroll
    for (int i = 0; i < 16; ++i) O[i] = (f32x4){0.f, 0.f, 0.f, 0.f};
    float lsum[4] = {0.f, 0.f, 0.f, 0.f};

    // V register fragments: lane reads V[c = w*64 + cj*16 + l15][kt*32 + quad*8 ..+8]
    const unsigned short* Vlane = Vg + (size_t)(w * 64 + l15) * NN + q8;
    short8 VA[4], VB[4];

    auto issueK = [&](int kt) {
        _Float16* Kd = Ksh + (size_t)(kt & 3) * 4096;
        const _Float16* gk = Kb + (size_t)kt * 4096;
        dma16(Kd + (w * 2 + 0) * 512, gk + (w * 2 + 0) * 512 + lane * 8);
        dma16(Kd + (w * 2 + 1) * 512, gk + (w * 2 + 1) * 512 + lane * 8);
    };
    auto loadV = [&](int kt, short8* Vd) {
#pragma unroll
        for (int cj = 0; cj < 4; ++cj)
            Vd[cj] = *(const short8*)(Vlane + (size_t)cj * 16 * NN + kt * 32);
    };

    // S' = (Q*log2e) K^T over one 32-key tile; P = 2^S' packed bf16 into Pc
    auto Sphase = [&](int kt, unsigned short* Pc) {
        const _Float16* Kc = Ksh + (size_t)(kt & 3) * 4096;
        f32x4 S0 = {0.f, 0.f, 0.f, 0.f}, S1 = {0.f, 0.f, 0.f, 0.f};
        __builtin_amdgcn_s_setprio(1);
#pragma unroll
        for (int s = 0; s < 4; ++s) {
            const int kc = 4 * s + quad;          // K k-chunk (8 o's)
            const int sw = (kc & 7) << 2;
            const int x0 = (l15 + sw) & 31;
            half8 kf0 = *(const half8*)(Kc + (kc * 32 + x0) * 8);
            half8 kf1 = *(const half8*)(Kc + (kc * 32 + (x0 ^ 16)) * 8);
            S0 = __builtin_amdgcn_mfma_f32_16x16x32_f16(Qf[s], kf0, S0, 0, 0, 0);
            S1 = __builtin_amdgcn_mfma_f32_16x16x32_f16(Qf[s], kf1, S1, 0, 0, 0);
        }
        __builtin_amdgcn_s_setprio(0);

        f32x4 E0, E1;
#pragma unroll
        for (int r = 0; r < 4; ++r) {
            E0[r] = exp2f(S0[r]);
            E1[r] = exp2f(S1[r]);
            lsum[r] += E0[r] + E1[r];
        }
        // lane^1 exchange via DPP (VALU), pack via v_cvt_pk_bf16_f32
        f32x4 P0, P1;
#pragma unroll
        for (int r = 0; r < 4; ++r) { P0[r] = dpp_xor1(E0[r]); P1[r] = dpp_xor1(E1[r]); }
        const int odd = l15 & 1;
        unsigned short* wp0 = Pc + w * 640
                            + (((quad << 2) + (odd << 1)) * 40) + (l15 & ~1);
        unsigned int pk0 = cvt_pk_bf16(odd ? P0[2] : E0[0], odd ? E0[2] : P0[0]);
        unsigned int pk1 = cvt_pk_bf16(odd ? P0[3] : E0[1], odd ? E0[3] : P0[1]);
        unsigned int pk2 = cvt_pk_bf16(odd ? P1[2] : E1[0], odd ? E1[2] : P1[0]);
        unsigned int pk3 = cvt_pk_bf16(odd ? P1[3] : E1[1], odd ? E1[3] : P1[1]);
        *(unsigned int*)&wp0[0]  = pk0;
        *(unsigned int*)&wp0[40] = pk1;
        *(unsigned int*)&wp0[16] = pk2;
        *(unsigned int*)&wp0[56] = pk3;
    };

    // PV: wave owns c-slice w*64..+63, all 64 n; V fragments from registers
    auto PVphase = [&](const unsigned short* Pc, const short8* Vc) {
        short8 pf[4];
#pragma unroll
        for (int ni = 0; ni < 4; ++ni)
            pf[ni] = *(const short8*)(Pc + (ni * 16 + l15) * 40 + q8);
        __builtin_amdgcn_s_setprio(1);
#pragma unroll
        for (int cj = 0; cj < 4; ++cj) {
            short8 vf = Vc[cj];
#pragma unroll
            for (int ni = 0; ni < 4; ++ni)
                O[ni * 4 + cj] = __builtin_amdgcn_mfma_f32_16x16x32_bf16(pf[ni], vf, O[ni * 4 + cj], 0, 0, 0);
        }
        __builtin_amdgcn_s_setprio(0);
    };

    issueK(0); issueK(1);
    loadV(0, VA); loadV(1, VB);
    __syncthreads();   // K0,K1 DMA + VA,VB loads drained

#pragma unroll 1
    for (int kt = 0; kt < 128; kt += 2) {
        // K prefetch-2: buffer (kt+2)&3 last read in Sphase(kt-2) pre-B(kt-2);
        // this issue is post-B(kt-1) -> 2-barrier WAR separation.
        if (kt + 2 < 128) issueK(kt + 2);
        Sphase(kt, Psh + (size_t)(kt & 3) * 2560);
        __syncthreads();               // P(kt) visible; K(kt+1) DMA drained
        PVphase(Psh + (size_t)(kt & 3) * 2560, VA);
        if (kt + 2 < 128) loadV(kt + 2, VA);   // regs: no cross-wave hazard

        if (kt + 3 < 128) issueK(kt + 3);      // post-B(kt); last read pre-B(kt-1)
        Sphase(kt + 1, Psh + (size_t)((kt + 1) & 3) * 2560);
        __syncthreads();               // P(kt+1) visible; K(kt+2) DMA drained
        PVphase(Psh + (size_t)((kt + 1) & 3) * 2560, VB);
        if (kt + 3 < 128) loadV(kt + 3, VB);
    }

    // ---- epilogue: row sums -> Lsh, divide, vectorized store ----
#pragma unroll
    for (int r = 0; r < 4; ++r) {
        float s = lsum[r];
        s += __shfl_xor(s, 1);
        s += __shfl_xor(s, 2);
        s += __shfl_xor(s, 4);
        s += __shfl_xor(s, 8);
        if (l15 == 0) Lsh[w * 16 + (quad << 2) + r] = s;
    }
    __syncthreads();
    float* ob = out + (size_t)b * CIN * NN + q0;
#pragma unroll
    for (int ni = 0; ni < 4; ++ni) {
        const f32x4 lv = *(const f32x4*)&Lsh[ni * 16 + (quad << 2)];
        f32x4 linv;
#pragma unroll
        for (int r = 0; r < 4; ++r) linv[r] = 1.0f / lv[r];
        const int nb = ni * 16 + (quad << 2);
#pragma unroll
        for (int cj = 0; cj < 4; ++cj) {
            const int c = w * 64 + cj * 16 + l15;
            f32x4 val = O[ni * 4 + cj];
#pragma unroll
            for (int r = 0; r < 4; ++r) val[r] *= linv[r];
            *(f32x4*)(ob + (size_t)c * NN + nb) = val;
        }
    }
}

extern "C" void kernel_launch(void* const* d_in, const int* in_sizes, int n_in,
                              void* d_out, int out_size, void* d_ws, size_t ws_size,
                              hipStream_t stream) {
    const float* p  = (const float*)d_in[0];
    const float* bv = (const float*)d_in[1];
    const float* Wq = (const float*)d_in[2];
    const float* bq = (const float*)d_in[3];
    const float* Wk = (const float*)d_in[4];
    const float* bk = (const float*)d_in[5];
    float* outp = (float*)d_out;

    char* ws = (char*)d_ws;
    const size_t szQ = (size_t)B_ * NN * COUT * 2;   // 8.4 MB (fp16)
    const size_t szV = (size_t)B_ * NN * CIN * 2;    // 16.8 MB (bf16)
    const size_t szW = (size_t)COUT * CIN * 2;       // 64 KB
    _Float16*       Qh  = (_Float16*)ws;
    _Float16*       Ktt = (_Float16*)(ws + szQ);
    unsigned short* Vb  = (unsigned short*)(ws + 2 * szQ);
    _Float16*       Whq = (_Float16*)(ws + 2 * szQ + szV);
    _Float16*       Whk = (_Float16*)(ws + 2 * szQ + szV + szW);
    float*          bqs = (float*)(ws + 2 * szQ + szV + 2 * szW);

    cvt_w<<<64, 256, 0, stream>>>(Wq, Wk, bq, Whq, Whk, bqs);
    proj3<<<512, 256, 0, stream>>>(p,  Whq, bqs, Qh, (_Float16*)nullptr, (unsigned short*)nullptr);
    proj3<<<512, 256, 0, stream>>>(bv, Whk, bk,  (_Float16*)nullptr, Ktt, Vb);
    flash_kernel<<<512, 256, 0, stream>>>(Qh, Ktt, Vb, outp);
}

// Round 5
// 285.648 us; speedup vs baseline: 1.0650x; 1.0650x over previous
//
#include <hip/hip_runtime.h>
#include <hip/hip_bf16.h>
#include <math.h>

// SpatialAttention B=8, C_IN=256 (d_v), C_OUT=128 (d_qk), N=4096.
// Round 12 (= r11 with the cvt_pkrtz type fix): flash is byte-identical to
// the verified 162.4us r8 version (V staged through LDS via DMA triple-
// buffer; 1 barrier per k-tile). proj3: LDS transpose deleted; MFMA
// A-fragments load directly from global (per (s,j) one instruction reads
// 4 c-rows x 64B contiguous, each element exactly once), packed in-register
// via v_cvt_pkrtz. K-pass runs the Vb row-pass first to warm L2. W fragment
// loads double-buffered across s. LDS only holds epilogue staging.
//   cvt_w : Wq*log2e, Wk -> fp16; bqs = bq*log2e          (unchanged)
//   flash : S mfma f16, P = 2^(S') unnormalized bf16, PV mfma bf16,
//           divide-by-l epilogue.

#define B_   8
#define CIN  256
#define COUT 128
#define NN   4096

typedef _Float16 half8  __attribute__((ext_vector_type(8)));
typedef short    short8 __attribute__((ext_vector_type(8)));
typedef float    f32x4  __attribute__((ext_vector_type(4)));

#define LOG2E 1.44269504088896340736f

__device__ __forceinline__ unsigned short f2h(float f) {
    union { _Float16 h; unsigned short u; } v; v.h = (_Float16)f;
    return v.u;
}
// packed f32x2 -> bf16x2 in one VALU op (no builtin on gfx950; inline asm)
__device__ __forceinline__ unsigned int cvt_pk_bf16(float lo, float hi) {
    unsigned int r;
    asm("v_cvt_pk_bf16_f32 %0, %1, %2" : "=v"(r) : "v"(lo), "v"(hi));
    return r;
}
// packed f32x2 -> f16x2 (RTZ) in one VALU op; builtin returns __fp16x2
__device__ __forceinline__ unsigned int pkrtz(float lo, float hi) {
    typedef __fp16 fp16x2 __attribute__((ext_vector_type(2)));
    union { fp16x2 h; unsigned int u; } c;
    c.h = __builtin_amdgcn_cvt_pkrtz(lo, hi);
    return c.u;
}
// lane^1 exchange on the VALU pipe: DPP quad_perm [1,0,3,2] (ctrl 0xB1)
__device__ __forceinline__ float dpp_xor1(float x) {
    union { float f; int i; } u; u.f = x;
    u.i = __builtin_amdgcn_mov_dpp(u.i, 0xB1, 0xF, 0xF, true);
    return u.f;
}
// async 16B global->LDS; LDS dest = wave-uniform base + lane*16
__device__ __forceinline__ void dma16(void* lds, const void* g) {
    __builtin_amdgcn_global_load_lds(
        (const __attribute__((address_space(1))) unsigned int*)g,
        (__attribute__((address_space(3))) unsigned int*)lds,
        16, 0, 0);
}

// ---- weights: Whq = Wq*log2e (fp16), Whk = Wk (fp16); bqs = bq*log2e ----
__global__ __launch_bounds__(256) void cvt_w(const float* __restrict__ Wq,
                                             const float* __restrict__ Wk,
                                             const float* __restrict__ bq,
                                             _Float16* __restrict__ Whq,
                                             _Float16* __restrict__ Whk,
                                             float* __restrict__ bqs) {
    const int bx = blockIdx.x, t = threadIdx.x;
    const int isK = (bx >= 32);
    const float* src = isK ? Wk : Wq;
    _Float16* dst = isK ? Whk : Whq;
    const float scale = isK ? 1.0f : LOG2E;
    const int idx = (bx & 31) * 256 + t;
    float4 v = ((const float4*)src)[idx];
    unsigned long long pk = (unsigned long long)f2h(v.x * scale)
                          | ((unsigned long long)f2h(v.y * scale) << 16)
                          | ((unsigned long long)f2h(v.z * scale) << 32)
                          | ((unsigned long long)f2h(v.w * scale) << 48);
    ((unsigned long long*)dst)[idx] = pk;
    if (bx == 0 && t < COUT) bqs[t] = bq[t] * LOG2E;
}

// ---- projection; Q pass -> outN, K pass -> outT (swizzled tiled) + Vb ----
// No LDS transpose: A-fragments load straight from global (fully coalesced
// 64B segments, each element once), packed fp16 in-register via cvt_pkrtz.
__global__ __launch_bounds__(256) void proj3(const float* __restrict__ X,     // [B][CIN][NN] fp32
                                             const _Float16* __restrict__ Wh, // [COUT][CIN] fp16
                                             const float* __restrict__ bias,  // [COUT] fp32
                                             _Float16* __restrict__ outN,     // [B][NN][COUT] or null
                                             _Float16* __restrict__ outT,     // tiled K or null
                                             unsigned short* __restrict__ Vb) // [B][CIN][NN] bf16 / null
{
    __shared__ __align__(16) unsigned short T[64 * 136];   // epilogue staging only (17KB)
    const int bx = blockIdx.x, b = bx >> 6, n0 = (bx & 63) << 6;
    const int t  = threadIdx.x;

    // ---- Vb pass (K projection only): bf16 convert + store; warms L2 ----
    if (Vb) {
        const int cr = t >> 2;
        const int nch = (t & 3) << 4;
#pragma unroll
        for (int it = 0; it < 4; ++it) {
            const int c = it * 64 + cr;
            const float* src = X + ((size_t)(b * CIN + c) * NN + n0 + nch);
            unsigned int o2[8];
#pragma unroll
            for (int k = 0; k < 4; ++k) {
                float4 f = *(const float4*)(src + k * 4);
                o2[k * 2]     = cvt_pk_bf16(f.x, f.y);
                o2[k * 2 + 1] = cvt_pk_bf16(f.z, f.w);
            }
            unsigned short* dst = Vb + (size_t)(b * CIN + c) * NN + n0 + nch;
            *(int4*)dst = *(int4*)&o2[0];
            *(int4*)(dst + 8) = *(int4*)&o2[4];
        }
    }

    const int w = t >> 6, lane = t & 63, l15 = lane & 15, quad = lane >> 4, q8 = quad * 8;

    // ---- A fragments from global: lane (l15,quad) of wave w holds
    // A[n = n0 + w*16 + l15][c = s*32 + q8 + j], j = 0..7
    half8 a[8];
    {
        const float* Xa = X + ((size_t)(b * CIN + q8) * NN) + n0 + w * 16 + l15;
#pragma unroll
        for (int s = 0; s < 8; ++s) {
            const float* xs = Xa + (size_t)s * 32 * NN;
            float av[8];
#pragma unroll
            for (int j = 0; j < 8; ++j) av[j] = xs[(size_t)j * NN];
            union { half8 h; unsigned int u[4]; } af;
#pragma unroll
            for (int j = 0; j < 4; ++j) af.u[j] = pkrtz(av[2 * j], av[2 * j + 1]);
            a[s] = af.h;
        }
    }

    // ---- GEMM: D[og] += a[s] * W-frag, W loads double-buffered over s ----
    f32x4 D[8];
#pragma unroll
    for (int og = 0; og < 8; ++og) D[og] = (f32x4){0.f, 0.f, 0.f, 0.f};
    const _Float16* wbase = Wh + (size_t)l15 * CIN + q8;
    half8 wf[2][8];
#pragma unroll
    for (int og = 0; og < 8; ++og)
        wf[0][og] = *(const half8*)(wbase + og * 16 * CIN);
#pragma unroll
    for (int s = 0; s < 8; ++s) {
        if (s < 7) {
            const _Float16* wp = wbase + (s + 1) * 32;
#pragma unroll
            for (int og = 0; og < 8; ++og)
                wf[(s + 1) & 1][og] = *(const half8*)(wp + og * 16 * CIN);
        }
#pragma unroll
        for (int og = 0; og < 8; ++og)
            D[og] = __builtin_amdgcn_mfma_f32_16x16x32_f16(a[s], wf[s & 1][og], D[og], 0, 0, 0);
    }

    // ---- epilogue: stage through LDS, coalesced int4 dump (r10-proven) ----
    const int nrow = w * 16 + quad * 4;   // local n
    if (outT) {
        // tiled-swizzled K layout: 2 local tiles x 4096 halfs,
        // tile-local addr = (c*32 + ((m + 4*(c&7)) & 31))*8 + (o&7)
#pragma unroll
        for (int og = 0; og < 8; ++og) {
            const int o = og * 16 + l15;
            const float bo = bias[o];
            const int c = o >> 3, j = o & 7;
            const int sw = (c & 7) << 2;
#pragma unroll
            for (int r2 = 0; r2 < 4; ++r2) {
                const int n = nrow + r2;
                const int tl = n >> 5, m = n & 31;
                T[tl * 4096 + (c * 32 + ((m + sw) & 31)) * 8 + j] = f2h(D[og][r2] + bo);
            }
        }
        __syncthreads();
        // dump 16KB contiguous (block owns global tiles n0/32, n0/32+1)
        _Float16* dstk = outT + ((size_t)(b * 128 + (n0 >> 5)) * 4096 + t * 32);
        const unsigned short* srck = T + t * 32;
#pragma unroll
        for (int k = 0; k < 4; ++k)
            ((int4*)dstk)[k] = ((const int4*)srck)[k];
    } else {
        // stage [n][o] fp16, row stride 136 halfs (272B, 16B-aligned rows)
#pragma unroll
        for (int og = 0; og < 8; ++og) {
            const int o = og * 16 + l15;
            const float bo = bias[o];
#pragma unroll
            for (int r2 = 0; r2 < 4; ++r2)
                T[(nrow + r2) * 136 + o] = f2h(D[og][r2] + bo);
        }
        __syncthreads();
        const int n = t >> 2, seg = t & 3;
        const unsigned short* srcp = T + n * 136 + seg * 32;
        _Float16* dstp = outN + ((size_t)(b * NN + n0 + n) * COUT + seg * 32);
#pragma unroll
        for (int k = 0; k < 4; ++k)
            ((int4*)dstp)[k] = ((const int4*)srcp)[k];
    }
}

// ---- flash attention: single barrier per k-tile, c-split PV ----
// (byte-identical to the verified 162.4us round-8 kernel)
// Q fp16 [b][4096][128] (pre-scaled by log2e); Ktt fp16 swizzled-tiled;
// V bf16 [b][256][4096]; out fp32 [b][256][4096]
// Buffers: K double (8KB x2), V triple (16KB x3), P double (5KB x2) = 74.25KB
__global__ __launch_bounds__(256, 2) void flash_kernel(const _Float16* __restrict__ Q,
                                                       const _Float16* __restrict__ Ktt,
                                                       const unsigned short* __restrict__ V,
                                                       float* __restrict__ out) {
    __shared__ __align__(16) _Float16       K0sh[32 * 128];
    __shared__ __align__(16) _Float16       K1sh[32 * 128];
    __shared__ __align__(16) unsigned short V0sh[256 * 32];
    __shared__ __align__(16) unsigned short V1sh[256 * 32];
    __shared__ __align__(16) unsigned short V2sh[256 * 32];
    __shared__ __align__(16) unsigned short P0sh[64 * 40];
    __shared__ __align__(16) unsigned short P1sh[64 * 40];
    __shared__ __align__(16) float          Lsh[64];

    const int bx   = blockIdx.x;          // 512 = B * 64 q-tiles
    const int b    = bx >> 6;
    const int q0   = (bx & 63) << 6;
    const int t    = threadIdx.x;
    const int w    = t >> 6;
    const int lane = t & 63;
    const int l15  = lane & 15;
    const int quad = lane >> 4;
    const int q8   = quad * 8;

    const _Float16* Qg = Q + (size_t)b * NN * COUT;
    const _Float16* Kb = Ktt + (size_t)b * 128 * 4096;   // 128 tiles x 4096 halfs
    const unsigned short* Vg = V + (size_t)b * CIN * NN;

    // Q fragments: wave w owns S rows q0+w*16 .. +15, resident all kernel
    half8 Qf[4];
    {
        const _Float16* qr = Qg + (size_t)(q0 + w * 16 + l15) * COUT;
#pragma unroll
        for (int s = 0; s < 4; ++s)
            Qf[s] = *(const half8*)(qr + s * 32 + q8);
    }

    f32x4 O[16];   // O[ni*4+cj]: n-block ni (16 n), c = w*64 + cj*16 + l15
#pragma unroll
    for (int i = 0; i < 16; ++i) O[i] = (f32x4){0.f, 0.f, 0.f, 0.f};
    float lsum[4] = {0.f, 0.f, 0.f, 0.f};

    // V DMA source remap (layout: chunk(c,mq) at position c*4 + ((mq+(c>>1))&3))
    const int vmq   = ((lane & 3) - ((lane >> 3) & 3)) & 3;   // mq this lane fetches
    const int vcrow = lane >> 2;                              // row-within-16 group
    // V read swizzle (hoisted): slot = (quad + (l15>>1)) & 3
    const int vslot = (quad + (l15 >> 1)) & 3;

    auto issueK = [&](int kt, _Float16* Kd) {
        const _Float16* gk = Kb + (size_t)kt * 4096;
        dma16(Kd + (w * 2 + 0) * 512, gk + (w * 2 + 0) * 512 + lane * 8);
        dma16(Kd + (w * 2 + 1) * 512, gk + (w * 2 + 1) * 512 + lane * 8);
    };
    auto issueV = [&](int kt, unsigned short* Vd) {
        const int k0 = kt << 5;
#pragma unroll
        for (int i = 0; i < 4; ++i) {
            const int cc = (w * 4 + i) * 16 + vcrow;
            dma16(Vd + (w * 4 + i) * 512,
                  Vg + (size_t)cc * NN + k0 + vmq * 8);
        }
    };

    // one k-tile (32 keys), single barrier:
    //   issueK(kt+1)->Kn ; S from Kc ; exp ; pack -> Pc ; BARRIER
    //   (drains K(kt+1) + V(kt+1)) ; issueV(kt+2)->Vn2 ; PV from Pc,Va
    auto halfstep = [&](int kt, const _Float16* Kc, _Float16* Kn,
                        const unsigned short* Va, unsigned short* Vn2,
                        unsigned short* Pc) {
        if (kt + 1 < 128) issueK(kt + 1, Kn);     // flies during S; drains at barrier

        // ---- S' = (Q*log2e) K^T : wave's 16 n rows x 32 m ----
        f32x4 S0 = {0.f, 0.f, 0.f, 0.f}, S1 = {0.f, 0.f, 0.f, 0.f};
        __builtin_amdgcn_s_setprio(1);
#pragma unroll
        for (int s = 0; s < 4; ++s) {
            const int kc = 4 * s + quad;          // K k-chunk (8 o's)
            const int sw = (kc & 7) << 2;
            const int x0 = (l15 + sw) & 31;
            half8 kf0 = *(const half8*)(Kc + (kc * 32 + x0) * 8);
            half8 kf1 = *(const half8*)(Kc + (kc * 32 + (x0 ^ 16)) * 8);
            S0 = __builtin_amdgcn_mfma_f32_16x16x32_f16(Qf[s], kf0, S0, 0, 0, 0);
            S1 = __builtin_amdgcn_mfma_f32_16x16x32_f16(Qf[s], kf1, S1, 0, 0, 0);
        }
        __builtin_amdgcn_s_setprio(0);

        // ---- P = 2^S' (unnormalized e^S); accumulate l ----
        f32x4 E0, E1;
#pragma unroll
        for (int r = 0; r < 4; ++r) {
            E0[r] = exp2f(S0[r]);
            E1[r] = exp2f(S1[r]);
            lsum[r] += E0[r] + E1[r];
        }
        // lane^1 exchange via DPP (VALU), pack via v_cvt_pk_bf16_f32
        {
            f32x4 P0, P1;
#pragma unroll
            for (int r = 0; r < 4; ++r) { P0[r] = dpp_xor1(E0[r]); P1[r] = dpp_xor1(E1[r]); }
            const int odd = l15 & 1;
            unsigned short* wp0 = Pc + w * 640
                                + (((quad << 2) + (odd << 1)) * 40) + (l15 & ~1);
            unsigned int pk0 = cvt_pk_bf16(odd ? P0[2] : E0[0], odd ? E0[2] : P0[0]);
            unsigned int pk1 = cvt_pk_bf16(odd ? P0[3] : E0[1], odd ? E0[3] : P0[1]);
            unsigned int pk2 = cvt_pk_bf16(odd ? P1[2] : E1[0], odd ? E1[2] : P1[0]);
            unsigned int pk3 = cvt_pk_bf16(odd ? P1[3] : E1[1], odd ? E1[3] : P1[1]);
            *(unsigned int*)&wp0[0]  = pk0;
            *(unsigned int*)&wp0[40] = pk1;
            *(unsigned int*)&wp0[16] = pk2;
            *(unsigned int*)&wp0[56] = pk3;
        }

        __syncthreads();   // P visible; K(kt+1) and V(kt+1) DMA drained

        if (kt + 2 < 128) issueV(kt + 2, Vn2);    // full halfstep of flight

        // ---- PV: wave owns c-slice w*64..+63, all 64 n ----
        {
            short8 pf[4];
#pragma unroll
            for (int ni = 0; ni < 4; ++ni)
                pf[ni] = *(const short8*)(Pc + (ni * 16 + l15) * 40 + q8);
            const unsigned short* vb = Va + (w * 64 + l15) * 32 + vslot * 8;
            __builtin_amdgcn_s_setprio(1);
#pragma unroll
            for (int cj = 0; cj < 4; ++cj) {
                short8 vf = *(const short8*)(vb + cj * 512);   // +16 c rows
#pragma unroll
                for (int ni = 0; ni < 4; ++ni)
                    O[ni * 4 + cj] = __builtin_amdgcn_mfma_f32_16x16x32_bf16(pf[ni], vf, O[ni * 4 + cj], 0, 0, 0);
            }
            __builtin_amdgcn_s_setprio(0);
        }
        // no trailing barrier: next tile's P goes to the other P buffer,
        // next K DMA targets the buffer whose readers finished pre-barrier,
        // V DMA two tiles ahead targets the slot last read before the barrier.
    };

    issueK(0, K0sh);
    issueV(0, V0sh);
    issueV(1, V1sh);
    __syncthreads();

    _Float16*       Kc = K0sh; _Float16*       Kn = K1sh;
    unsigned short* Va = V0sh; unsigned short* Vm = V1sh; unsigned short* Vn2 = V2sh;
    unsigned short* Pc = P0sh; unsigned short* Pn = P1sh;
#pragma unroll 1
    for (int kt = 0; kt < 128; ++kt) {
        halfstep(kt, Kc, Kn, Va, Vn2, Pc);
        _Float16* tk = Kc; Kc = Kn; Kn = tk;
        unsigned short* tv = Va; Va = Vm; Vm = Vn2; Vn2 = tv;
        unsigned short* tp = Pc; Pc = Pn; Pn = tp;
    }

    // ---- epilogue: row sums -> Lsh, divide, vectorized store ----
#pragma unroll
    for (int r = 0; r < 4; ++r) {
        float s = lsum[r];
        s += __shfl_xor(s, 1);
        s += __shfl_xor(s, 2);
        s += __shfl_xor(s, 4);
        s += __shfl_xor(s, 8);
        if (l15 == 0) Lsh[w * 16 + (quad << 2) + r] = s;
    }
    __syncthreads();
    float* ob = out + (size_t)b * CIN * NN + q0;
#pragma unroll
    for (int ni = 0; ni < 4; ++ni) {
        const f32x4 lv = *(const f32x4*)&Lsh[ni * 16 + (quad << 2)];
        f32x4 linv;
#pragma unroll
        for (int r = 0; r < 4; ++r) linv[r] = 1.0f / lv[r];
        const int nb = ni * 16 + (quad << 2);
#pragma unroll
        for (int cj = 0; cj < 4; ++cj) {
            const int c = w * 64 + cj * 16 + l15;
            f32x4 val = O[ni * 4 + cj];
#pragma unroll
            for (int r = 0; r < 4; ++r) val[r] *= linv[r];
            *(f32x4*)(ob + (size_t)c * NN + nb) = val;
        }
    }
}

extern "C" void kernel_launch(void* const* d_in, const int* in_sizes, int n_in,
                              void* d_out, int out_size, void* d_ws, size_t ws_size,
                              hipStream_t stream) {
    const float* p  = (const float*)d_in[0];
    const float* bv = (const float*)d_in[1];
    const float* Wq = (const float*)d_in[2];
    const float* bq = (const float*)d_in[3];
    const float* Wk = (const float*)d_in[4];
    const float* bk = (const float*)d_in[5];
    float* outp = (float*)d_out;

    char* ws = (char*)d_ws;
    const size_t szQ = (size_t)B_ * NN * COUT * 2;   // 8.4 MB (fp16)
    const size_t szV = (size_t)B_ * NN * CIN * 2;    // 16.8 MB (bf16)
    const size_t szW = (size_t)COUT * CIN * 2;       // 64 KB
    _Float16*       Qh  = (_Float16*)ws;
    _Float16*       Ktt = (_Float16*)(ws + szQ);
    unsigned short* Vb  = (unsigned short*)(ws + 2 * szQ);
    _Float16*       Whq = (_Float16*)(ws + 2 * szQ + szV);
    _Float16*       Whk = (_Float16*)(ws + 2 * szQ + szV + szW);
    float*          bqs = (float*)(ws + 2 * szQ + szV + 2 * szW);

    cvt_w<<<64, 256, 0, stream>>>(Wq, Wk, bq, Whq, Whk, bqs);
    proj3<<<512, 256, 0, stream>>>(p,  Whq, bqs, Qh, (_Float16*)nullptr, (unsigned short*)nullptr);
    proj3<<<512, 256, 0, stream>>>(bv, Whk, bk,  (_Float16*)nullptr, Ktt, Vb);
    flash_kernel<<<512, 256, 0, stream>>>(Qh, Ktt, Vb, outp);
}

// Round 6
// 281.432 us; speedup vs baseline: 1.0810x; 1.0150x over previous
//
#include <hip/hip_runtime.h>
#include <hip/hip_bf16.h>
#include <math.h>

// SpatialAttention B=8, C_IN=256 (d_v), C_OUT=128 (d_qk), N=4096.
// Round 13: Q-proj and K-proj merged into ONE 1024-block launch (proj_all):
// doubles resident blocks/CU (2->4) to hide the cold-HBM A-load latency that
// four rounds of inner-loop rewrites never moved, overlaps the p/b HBM
// streams, removes one launch/drain boundary. W fragments single-buffered
// (-32 VGPR) + __launch_bounds__(256,3) so the occupancy materializes.
// flash & cvt_w frozen byte-identical to the verified 162-164us version.
//   cvt_w : Wq*log2e, Wk -> fp16; bqs = bq*log2e
//   flash : S mfma f16, P = 2^(S') unnormalized bf16, PV mfma bf16,
//           divide-by-l epilogue.

#define B_   8
#define CIN  256
#define COUT 128
#define NN   4096

typedef _Float16 half8  __attribute__((ext_vector_type(8)));
typedef short    short8 __attribute__((ext_vector_type(8)));
typedef float    f32x4  __attribute__((ext_vector_type(4)));

#define LOG2E 1.44269504088896340736f

__device__ __forceinline__ unsigned short f2h(float f) {
    union { _Float16 h; unsigned short u; } v; v.h = (_Float16)f;
    return v.u;
}
// packed f32x2 -> bf16x2 in one VALU op (no builtin on gfx950; inline asm)
__device__ __forceinline__ unsigned int cvt_pk_bf16(float lo, float hi) {
    unsigned int r;
    asm("v_cvt_pk_bf16_f32 %0, %1, %2" : "=v"(r) : "v"(lo), "v"(hi));
    return r;
}
// packed f32x2 -> f16x2 (RTZ) in one VALU op; builtin returns __fp16x2
__device__ __forceinline__ unsigned int pkrtz(float lo, float hi) {
    typedef __fp16 fp16x2 __attribute__((ext_vector_type(2)));
    union { fp16x2 h; unsigned int u; } c;
    c.h = __builtin_amdgcn_cvt_pkrtz(lo, hi);
    return c.u;
}
// lane^1 exchange on the VALU pipe: DPP quad_perm [1,0,3,2] (ctrl 0xB1)
__device__ __forceinline__ float dpp_xor1(float x) {
    union { float f; int i; } u; u.f = x;
    u.i = __builtin_amdgcn_mov_dpp(u.i, 0xB1, 0xF, 0xF, true);
    return u.f;
}
// async 16B global->LDS; LDS dest = wave-uniform base + lane*16
__device__ __forceinline__ void dma16(void* lds, const void* g) {
    __builtin_amdgcn_global_load_lds(
        (const __attribute__((address_space(1))) unsigned int*)g,
        (__attribute__((address_space(3))) unsigned int*)lds,
        16, 0, 0);
}

// ---- weights: Whq = Wq*log2e (fp16), Whk = Wk (fp16); bqs = bq*log2e ----
__global__ __launch_bounds__(256) void cvt_w(const float* __restrict__ Wq,
                                             const float* __restrict__ Wk,
                                             const float* __restrict__ bq,
                                             _Float16* __restrict__ Whq,
                                             _Float16* __restrict__ Whk,
                                             float* __restrict__ bqs) {
    const int bx = blockIdx.x, t = threadIdx.x;
    const int isK = (bx >= 32);
    const float* src = isK ? Wk : Wq;
    _Float16* dst = isK ? Whk : Whq;
    const float scale = isK ? 1.0f : LOG2E;
    const int idx = (bx & 31) * 256 + t;
    float4 v = ((const float4*)src)[idx];
    unsigned long long pk = (unsigned long long)f2h(v.x * scale)
                          | ((unsigned long long)f2h(v.y * scale) << 16)
                          | ((unsigned long long)f2h(v.z * scale) << 32)
                          | ((unsigned long long)f2h(v.w * scale) << 48);
    ((unsigned long long*)dst)[idx] = pk;
    if (bx == 0 && t < COUT) bqs[t] = bq[t] * LOG2E;
}

// ---- merged projection: blocks 0..511 Q-pass (p -> Qh), 512..1023 K-pass
// (b -> Ktt swizzled-tiled + Vb bf16). A-fragments load straight from global
// (coalesced 64B segments, each element once), packed fp16 via cvt_pkrtz.
__global__ __launch_bounds__(256, 3) void proj_all(
        const float* __restrict__ P,     // [B][CIN][NN] fp32 (query input)
        const float* __restrict__ Bv,    // [B][CIN][NN] fp32 (key/value input)
        const _Float16* __restrict__ Whq,// [COUT][CIN] fp16 (prescaled log2e)
        const _Float16* __restrict__ Whk,// [COUT][CIN] fp16
        const float* __restrict__ bqs,   // [COUT] fp32 (prescaled log2e)
        const float* __restrict__ bk,    // [COUT] fp32
        _Float16* __restrict__ Qh,       // [B][NN][COUT] fp16
        _Float16* __restrict__ Ktt,      // tiled K fp16
        unsigned short* __restrict__ Vb) // [B][CIN][NN] bf16
{
    __shared__ __align__(16) unsigned short T[64 * 136];   // epilogue staging (17KB)
    const int bx = blockIdx.x;
    const int isK = bx >> 9;                 // 0: Q blocks, 1: K blocks
    const int bl  = bx & 511;
    const int b   = bl >> 6, n0 = (bl & 63) << 6;
    const int t   = threadIdx.x;

    const float*    X    = isK ? Bv  : P;
    const _Float16* Wh   = isK ? Whk : Whq;
    const float*    bias = isK ? bk  : bqs;

    // ---- Vb pass (K blocks only): bf16 convert + store; warms L2 ----
    if (isK) {
        const int cr = t >> 2;
        const int nch = (t & 3) << 4;
#pragma unroll
        for (int it = 0; it < 4; ++it) {
            const int c = it * 64 + cr;
            const float* src = X + ((size_t)(b * CIN + c) * NN + n0 + nch);
            unsigned int o2[8];
#pragma unroll
            for (int k = 0; k < 4; ++k) {
                float4 f = *(const float4*)(src + k * 4);
                o2[k * 2]     = cvt_pk_bf16(f.x, f.y);
                o2[k * 2 + 1] = cvt_pk_bf16(f.z, f.w);
            }
            unsigned short* dst = Vb + (size_t)(b * CIN + c) * NN + n0 + nch;
            *(int4*)dst = *(int4*)&o2[0];
            *(int4*)(dst + 8) = *(int4*)&o2[4];
        }
    }

    const int w = t >> 6, lane = t & 63, l15 = lane & 15, quad = lane >> 4, q8 = quad * 8;

    // ---- A fragments from global: lane (l15,quad) of wave w holds
    // A[n = n0 + w*16 + l15][c = s*32 + q8 + j], j = 0..7
    half8 a[8];
    {
        const float* Xa = X + ((size_t)(b * CIN + q8) * NN) + n0 + w * 16 + l15;
#pragma unroll
        for (int s = 0; s < 8; ++s) {
            const float* xs = Xa + (size_t)s * 32 * NN;
            float av[8];
#pragma unroll
            for (int j = 0; j < 8; ++j) av[j] = xs[(size_t)j * NN];
            union { half8 h; unsigned int u[4]; } af;
#pragma unroll
            for (int j = 0; j < 4; ++j) af.u[j] = pkrtz(av[2 * j], av[2 * j + 1]);
            a[s] = af.h;
        }
    }

    // ---- GEMM: D[og] += a[s] * W-frag (W single-buffered; L2-resident) ----
    f32x4 D[8];
#pragma unroll
    for (int og = 0; og < 8; ++og) D[og] = (f32x4){0.f, 0.f, 0.f, 0.f};
    const _Float16* wbase = Wh + (size_t)l15 * CIN + q8;
#pragma unroll
    for (int s = 0; s < 8; ++s) {
        const _Float16* wp = wbase + s * 32;
#pragma unroll
        for (int og = 0; og < 8; ++og) {
            half8 wfv = *(const half8*)(wp + og * 16 * CIN);
            D[og] = __builtin_amdgcn_mfma_f32_16x16x32_f16(a[s], wfv, D[og], 0, 0, 0);
        }
    }

    // ---- epilogue: stage through LDS, coalesced int4 dump ----
    const int nrow = w * 16 + quad * 4;   // local n
    if (isK) {
        // tiled-swizzled K layout: 2 local tiles x 4096 halfs,
        // tile-local addr = (c*32 + ((m + 4*(c&7)) & 31))*8 + (o&7)
#pragma unroll
        for (int og = 0; og < 8; ++og) {
            const int o = og * 16 + l15;
            const float bo = bias[o];
            const int c = o >> 3, j = o & 7;
            const int sw = (c & 7) << 2;
#pragma unroll
            for (int r2 = 0; r2 < 4; ++r2) {
                const int n = nrow + r2;
                const int tl = n >> 5, m = n & 31;
                T[tl * 4096 + (c * 32 + ((m + sw) & 31)) * 8 + j] = f2h(D[og][r2] + bo);
            }
        }
        __syncthreads();
        // dump 16KB contiguous (block owns global tiles n0/32, n0/32+1)
        _Float16* dstk = Ktt + ((size_t)(b * 128 + (n0 >> 5)) * 4096 + t * 32);
        const unsigned short* srck = T + t * 32;
#pragma unroll
        for (int k = 0; k < 4; ++k)
            ((int4*)dstk)[k] = ((const int4*)srck)[k];
    } else {
        // stage [n][o] fp16, row stride 136 halfs (272B, 16B-aligned rows)
#pragma unroll
        for (int og = 0; og < 8; ++og) {
            const int o = og * 16 + l15;
            const float bo = bias[o];
#pragma unroll
            for (int r2 = 0; r2 < 4; ++r2)
                T[(nrow + r2) * 136 + o] = f2h(D[og][r2] + bo);
        }
        __syncthreads();
        const int n = t >> 2, seg = t & 3;
        const unsigned short* srcp = T + n * 136 + seg * 32;
        _Float16* dstp = Qh + ((size_t)(b * NN + n0 + n) * COUT + seg * 32);
#pragma unroll
        for (int k = 0; k < 4; ++k)
            ((int4*)dstp)[k] = ((const int4*)srcp)[k];
    }
}

// ---- flash attention: single barrier per k-tile, c-split PV ----
// (byte-identical to the verified 162.4us round-8 kernel)
// Q fp16 [b][4096][128] (pre-scaled by log2e); Ktt fp16 swizzled-tiled;
// V bf16 [b][256][4096]; out fp32 [b][256][4096]
// Buffers: K double (8KB x2), V triple (16KB x3), P double (5KB x2) = 74.25KB
__global__ __launch_bounds__(256, 2) void flash_kernel(const _Float16* __restrict__ Q,
                                                       const _Float16* __restrict__ Ktt,
                                                       const unsigned short* __restrict__ V,
                                                       float* __restrict__ out) {
    __shared__ __align__(16) _Float16       K0sh[32 * 128];
    __shared__ __align__(16) _Float16       K1sh[32 * 128];
    __shared__ __align__(16) unsigned short V0sh[256 * 32];
    __shared__ __align__(16) unsigned short V1sh[256 * 32];
    __shared__ __align__(16) unsigned short V2sh[256 * 32];
    __shared__ __align__(16) unsigned short P0sh[64 * 40];
    __shared__ __align__(16) unsigned short P1sh[64 * 40];
    __shared__ __align__(16) float          Lsh[64];

    const int bx   = blockIdx.x;          // 512 = B * 64 q-tiles
    const int b    = bx >> 6;
    const int q0   = (bx & 63) << 6;
    const int t    = threadIdx.x;
    const int w    = t >> 6;
    const int lane = t & 63;
    const int l15  = lane & 15;
    const int quad = lane >> 4;
    const int q8   = quad * 8;

    const _Float16* Qg = Q + (size_t)b * NN * COUT;
    const _Float16* Kb = Ktt + (size_t)b * 128 * 4096;   // 128 tiles x 4096 halfs
    const unsigned short* Vg = V + (size_t)b * CIN * NN;

    // Q fragments: wave w owns S rows q0+w*16 .. +15, resident all kernel
    half8 Qf[4];
    {
        const _Float16* qr = Qg + (size_t)(q0 + w * 16 + l15) * COUT;
#pragma unroll
        for (int s = 0; s < 4; ++s)
            Qf[s] = *(const half8*)(qr + s * 32 + q8);
    }

    f32x4 O[16];   // O[ni*4+cj]: n-block ni (16 n), c = w*64 + cj*16 + l15
#pragma unroll
    for (int i = 0; i < 16; ++i) O[i] = (f32x4){0.f, 0.f, 0.f, 0.f};
    float lsum[4] = {0.f, 0.f, 0.f, 0.f};

    // V DMA source remap (layout: chunk(c,mq) at position c*4 + ((mq+(c>>1))&3))
    const int vmq   = ((lane & 3) - ((lane >> 3) & 3)) & 3;   // mq this lane fetches
    const int vcrow = lane >> 2;                              // row-within-16 group
    // V read swizzle (hoisted): slot = (quad + (l15>>1)) & 3
    const int vslot = (quad + (l15 >> 1)) & 3;

    auto issueK = [&](int kt, _Float16* Kd) {
        const _Float16* gk = Kb + (size_t)kt * 4096;
        dma16(Kd + (w * 2 + 0) * 512, gk + (w * 2 + 0) * 512 + lane * 8);
        dma16(Kd + (w * 2 + 1) * 512, gk + (w * 2 + 1) * 512 + lane * 8);
    };
    auto issueV = [&](int kt, unsigned short* Vd) {
        const int k0 = kt << 5;
#pragma unroll
        for (int i = 0; i < 4; ++i) {
            const int cc = (w * 4 + i) * 16 + vcrow;
            dma16(Vd + (w * 4 + i) * 512,
                  Vg + (size_t)cc * NN + k0 + vmq * 8);
        }
    };

    // one k-tile (32 keys), single barrier:
    //   issueK(kt+1)->Kn ; S from Kc ; exp ; pack -> Pc ; BARRIER
    //   (drains K(kt+1) + V(kt+1)) ; issueV(kt+2)->Vn2 ; PV from Pc,Va
    auto halfstep = [&](int kt, const _Float16* Kc, _Float16* Kn,
                        const unsigned short* Va, unsigned short* Vn2,
                        unsigned short* Pc) {
        if (kt + 1 < 128) issueK(kt + 1, Kn);     // flies during S; drains at barrier

        // ---- S' = (Q*log2e) K^T : wave's 16 n rows x 32 m ----
        f32x4 S0 = {0.f, 0.f, 0.f, 0.f}, S1 = {0.f, 0.f, 0.f, 0.f};
        __builtin_amdgcn_s_setprio(1);
#pragma unroll
        for (int s = 0; s < 4; ++s) {
            const int kc = 4 * s + quad;          // K k-chunk (8 o's)
            const int sw = (kc & 7) << 2;
            const int x0 = (l15 + sw) & 31;
            half8 kf0 = *(const half8*)(Kc + (kc * 32 + x0) * 8);
            half8 kf1 = *(const half8*)(Kc + (kc * 32 + (x0 ^ 16)) * 8);
            S0 = __builtin_amdgcn_mfma_f32_16x16x32_f16(Qf[s], kf0, S0, 0, 0, 0);
            S1 = __builtin_amdgcn_mfma_f32_16x16x32_f16(Qf[s], kf1, S1, 0, 0, 0);
        }
        __builtin_amdgcn_s_setprio(0);

        // ---- P = 2^S' (unnormalized e^S); accumulate l ----
        f32x4 E0, E1;
#pragma unroll
        for (int r = 0; r < 4; ++r) {
            E0[r] = exp2f(S0[r]);
            E1[r] = exp2f(S1[r]);
            lsum[r] += E0[r] + E1[r];
        }
        // lane^1 exchange via DPP (VALU), pack via v_cvt_pk_bf16_f32
        {
            f32x4 P0, P1;
#pragma unroll
            for (int r = 0; r < 4; ++r) { P0[r] = dpp_xor1(E0[r]); P1[r] = dpp_xor1(E1[r]); }
            const int odd = l15 & 1;
            unsigned short* wp0 = Pc + w * 640
                                + (((quad << 2) + (odd << 1)) * 40) + (l15 & ~1);
            unsigned int pk0 = cvt_pk_bf16(odd ? P0[2] : E0[0], odd ? E0[2] : P0[0]);
            unsigned int pk1 = cvt_pk_bf16(odd ? P0[3] : E0[1], odd ? E0[3] : P0[1]);
            unsigned int pk2 = cvt_pk_bf16(odd ? P1[2] : E1[0], odd ? E1[2] : P1[0]);
            unsigned int pk3 = cvt_pk_bf16(odd ? P1[3] : E1[1], odd ? E1[3] : P1[1]);
            *(unsigned int*)&wp0[0]  = pk0;
            *(unsigned int*)&wp0[40] = pk1;
            *(unsigned int*)&wp0[16] = pk2;
            *(unsigned int*)&wp0[56] = pk3;
        }

        __syncthreads();   // P visible; K(kt+1) and V(kt+1) DMA drained

        if (kt + 2 < 128) issueV(kt + 2, Vn2);    // full halfstep of flight

        // ---- PV: wave owns c-slice w*64..+63, all 64 n ----
        {
            short8 pf[4];
#pragma unroll
            for (int ni = 0; ni < 4; ++ni)
                pf[ni] = *(const short8*)(Pc + (ni * 16 + l15) * 40 + q8);
            const unsigned short* vb = Va + (w * 64 + l15) * 32 + vslot * 8;
            __builtin_amdgcn_s_setprio(1);
#pragma unroll
            for (int cj = 0; cj < 4; ++cj) {
                short8 vf = *(const short8*)(vb + cj * 512);   // +16 c rows
#pragma unroll
                for (int ni = 0; ni < 4; ++ni)
                    O[ni * 4 + cj] = __builtin_amdgcn_mfma_f32_16x16x32_bf16(pf[ni], vf, O[ni * 4 + cj], 0, 0, 0);
            }
            __builtin_amdgcn_s_setprio(0);
        }
        // no trailing barrier: next tile's P goes to the other P buffer,
        // next K DMA targets the buffer whose readers finished pre-barrier,
        // V DMA two tiles ahead targets the slot last read before the barrier.
    };

    issueK(0, K0sh);
    issueV(0, V0sh);
    issueV(1, V1sh);
    __syncthreads();

    _Float16*       Kc = K0sh; _Float16*       Kn = K1sh;
    unsigned short* Va = V0sh; unsigned short* Vm = V1sh; unsigned short* Vn2 = V2sh;
    unsigned short* Pc = P0sh; unsigned short* Pn = P1sh;
#pragma unroll 1
    for (int kt = 0; kt < 128; ++kt) {
        halfstep(kt, Kc, Kn, Va, Vn2, Pc);
        _Float16* tk = Kc; Kc = Kn; Kn = tk;
        unsigned short* tv = Va; Va = Vm; Vm = Vn2; Vn2 = tv;
        unsigned short* tp = Pc; Pc = Pn; Pn = tp;
    }

    // ---- epilogue: row sums -> Lsh, divide, vectorized store ----
#pragma unroll
    for (int r = 0; r < 4; ++r) {
        float s = lsum[r];
        s += __shfl_xor(s, 1);
        s += __shfl_xor(s, 2);
        s += __shfl_xor(s, 4);
        s += __shfl_xor(s, 8);
        if (l15 == 0) Lsh[w * 16 + (quad << 2) + r] = s;
    }
    __syncthreads();
    float* ob = out + (size_t)b * CIN * NN + q0;
#pragma unroll
    for (int ni = 0; ni < 4; ++ni) {
        const f32x4 lv = *(const f32x4*)&Lsh[ni * 16 + (quad << 2)];
        f32x4 linv;
#pragma unroll
        for (int r = 0; r < 4; ++r) linv[r] = 1.0f / lv[r];
        const int nb = ni * 16 + (quad << 2);
#pragma unroll
        for (int cj = 0; cj < 4; ++cj) {
            const int c = w * 64 + cj * 16 + l15;
            f32x4 val = O[ni * 4 + cj];
#pragma unroll
            for (int r = 0; r < 4; ++r) val[r] *= linv[r];
            *(f32x4*)(ob + (size_t)c * NN + nb) = val;
        }
    }
}

extern "C" void kernel_launch(void* const* d_in, const int* in_sizes, int n_in,
                              void* d_out, int out_size, void* d_ws, size_t ws_size,
                              hipStream_t stream) {
    const float* p  = (const float*)d_in[0];
    const float* bv = (const float*)d_in[1];
    const float* Wq = (const float*)d_in[2];
    const float* bq = (const float*)d_in[3];
    const float* Wk = (const float*)d_in[4];
    const float* bk = (const float*)d_in[5];
    float* outp = (float*)d_out;

    char* ws = (char*)d_ws;
    const size_t szQ = (size_t)B_ * NN * COUT * 2;   // 8.4 MB (fp16)
    const size_t szV = (size_t)B_ * NN * CIN * 2;    // 16.8 MB (bf16)
    const size_t szW = (size_t)COUT * CIN * 2;       // 64 KB
    _Float16*       Qh  = (_Float16*)ws;
    _Float16*       Ktt = (_Float16*)(ws + szQ);
    unsigned short* Vb  = (unsigned short*)(ws + 2 * szQ);
    _Float16*       Whq = (_Float16*)(ws + 2 * szQ + szV);
    _Float16*       Whk = (_Float16*)(ws + 2 * szQ + szV + szW);
    float*          bqs = (float*)(ws + 2 * szQ + szV + 2 * szW);

    cvt_w<<<64, 256, 0, stream>>>(Wq, Wk, bq, Whq, Whk, bqs);
    proj_all<<<1024, 256, 0, stream>>>(p, bv, Whq, Whk, bqs, bk, Qh, Ktt, Vb);
    flash_kernel<<<512, 256, 0, stream>>>(Qh, Ktt, Vb, outp);
}

// Round 7
// 275.818 us; speedup vs baseline: 1.1030x; 1.0204x over previous
//
#include <hip/hip_runtime.h>
#include <hip/hip_bf16.h>
#include <math.h>

// SpatialAttention B=8, C_IN=256 (d_v), C_OUT=128 (d_qk), N=4096.
// Round 14: Q-projection FUSED into flash's prologue — each flash block
// computes its own 64x128 Q tile from p (disjoint 64KB reads, 16 MFMA/wave,
// LDS staging aliased over the K/V buffers with 2-barrier separation).
// Deletes the Qh write+read round-trip (16.8 MB) and half of the stubborn
// ~110us projection pass that five inner-loop rewrites never moved.
// K/V-prep stays a separate kernel (K/V shared by 64 blocks; fusing would
// double flash compute). flash main loop frozen (verified 162us structure).
//   cvt_w  : Wq*log2e, Wk -> fp16; bqs = bq*log2e
//   kv_prep: b -> Ktt (swizzled tiled fp16) + Vb (bf16)
//   flash  : Q-proj prologue; S mfma f16, P = 2^(S') unnormalized bf16,
//            PV mfma bf16, divide-by-l epilogue.

#define B_   8
#define CIN  256
#define COUT 128
#define NN   4096

typedef _Float16 half8  __attribute__((ext_vector_type(8)));
typedef short    short8 __attribute__((ext_vector_type(8)));
typedef float    f32x4  __attribute__((ext_vector_type(4)));

#define LOG2E 1.44269504088896340736f

__device__ __forceinline__ unsigned short f2h(float f) {
    union { _Float16 h; unsigned short u; } v; v.h = (_Float16)f;
    return v.u;
}
// packed f32x2 -> bf16x2 in one VALU op (no builtin on gfx950; inline asm)
__device__ __forceinline__ unsigned int cvt_pk_bf16(float lo, float hi) {
    unsigned int r;
    asm("v_cvt_pk_bf16_f32 %0, %1, %2" : "=v"(r) : "v"(lo), "v"(hi));
    return r;
}
// packed f32x2 -> f16x2 (RTZ) in one VALU op; builtin returns __fp16x2
__device__ __forceinline__ unsigned int pkrtz(float lo, float hi) {
    typedef __fp16 fp16x2 __attribute__((ext_vector_type(2)));
    union { fp16x2 h; unsigned int u; } c;
    c.h = __builtin_amdgcn_cvt_pkrtz(lo, hi);
    return c.u;
}
// lane^1 exchange on the VALU pipe: DPP quad_perm [1,0,3,2] (ctrl 0xB1)
__device__ __forceinline__ float dpp_xor1(float x) {
    union { float f; int i; } u; u.f = x;
    u.i = __builtin_amdgcn_mov_dpp(u.i, 0xB1, 0xF, 0xF, true);
    return u.f;
}
// async 16B global->LDS; LDS dest = wave-uniform base + lane*16
__device__ __forceinline__ void dma16(void* lds, const void* g) {
    __builtin_amdgcn_global_load_lds(
        (const __attribute__((address_space(1))) unsigned int*)g,
        (__attribute__((address_space(3))) unsigned int*)lds,
        16, 0, 0);
}

// ---- weights: Whq = Wq*log2e (fp16), Whk = Wk (fp16); bqs = bq*log2e ----
__global__ __launch_bounds__(256) void cvt_w(const float* __restrict__ Wq,
                                             const float* __restrict__ Wk,
                                             const float* __restrict__ bq,
                                             _Float16* __restrict__ Whq,
                                             _Float16* __restrict__ Whk,
                                             float* __restrict__ bqs) {
    const int bx = blockIdx.x, t = threadIdx.x;
    const int isK = (bx >= 32);
    const float* src = isK ? Wk : Wq;
    _Float16* dst = isK ? Whk : Whq;
    const float scale = isK ? 1.0f : LOG2E;
    const int idx = (bx & 31) * 256 + t;
    float4 v = ((const float4*)src)[idx];
    unsigned long long pk = (unsigned long long)f2h(v.x * scale)
                          | ((unsigned long long)f2h(v.y * scale) << 16)
                          | ((unsigned long long)f2h(v.z * scale) << 32)
                          | ((unsigned long long)f2h(v.w * scale) << 48);
    ((unsigned long long*)dst)[idx] = pk;
    if (bx == 0 && t < COUT) bqs[t] = bq[t] * LOG2E;
}

// ---- K/V prep: b -> Ktt (swizzled tiled) + Vb (bf16). 512 blocks. ----
__global__ __launch_bounds__(256) void kv_prep(
        const float* __restrict__ Bv,    // [B][CIN][NN] fp32
        const _Float16* __restrict__ Whk,// [COUT][CIN] fp16
        const float* __restrict__ bk,    // [COUT] fp32
        _Float16* __restrict__ Ktt,      // tiled K fp16
        unsigned short* __restrict__ Vb) // [B][CIN][NN] bf16
{
    __shared__ __align__(16) unsigned short T[64 * 136];
    const int bx = blockIdx.x;
    const int b  = bx >> 6, n0 = (bx & 63) << 6;
    const int t  = threadIdx.x;

    // Vb pass: bf16 convert + store; warms L2 for the A-loads below
    {
        const int cr = t >> 2;
        const int nch = (t & 3) << 4;
#pragma unroll
        for (int it = 0; it < 4; ++it) {
            const int c = it * 64 + cr;
            const float* src = Bv + ((size_t)(b * CIN + c) * NN + n0 + nch);
            unsigned int o2[8];
#pragma unroll
            for (int k = 0; k < 4; ++k) {
                float4 f = *(const float4*)(src + k * 4);
                o2[k * 2]     = cvt_pk_bf16(f.x, f.y);
                o2[k * 2 + 1] = cvt_pk_bf16(f.z, f.w);
            }
            unsigned short* dst = Vb + (size_t)(b * CIN + c) * NN + n0 + nch;
            *(int4*)dst = *(int4*)&o2[0];
            *(int4*)(dst + 8) = *(int4*)&o2[4];
        }
    }

    const int w = t >> 6, lane = t & 63, l15 = lane & 15, quad = lane >> 4, q8 = quad * 8;

    // A fragments from global: lane holds Bv[c = s*32 + q8 + j][n0 + w*16 + l15]
    half8 a[8];
    {
        const float* Xa = Bv + ((size_t)(b * CIN + q8) * NN) + n0 + w * 16 + l15;
#pragma unroll
        for (int s = 0; s < 8; ++s) {
            const float* xs = Xa + (size_t)s * 32 * NN;
            float av[8];
#pragma unroll
            for (int j = 0; j < 8; ++j) av[j] = xs[(size_t)j * NN];
            union { half8 h; unsigned int u[4]; } af;
#pragma unroll
            for (int j = 0; j < 4; ++j) af.u[j] = pkrtz(av[2 * j], av[2 * j + 1]);
            a[s] = af.h;
        }
    }

    f32x4 D[8];
#pragma unroll
    for (int og = 0; og < 8; ++og) D[og] = (f32x4){0.f, 0.f, 0.f, 0.f};
    const _Float16* wbase = Whk + (size_t)l15 * CIN + q8;
#pragma unroll
    for (int s = 0; s < 8; ++s) {
        const _Float16* wp = wbase + s * 32;
#pragma unroll
        for (int og = 0; og < 8; ++og) {
            half8 wfv = *(const half8*)(wp + og * 16 * CIN);
            D[og] = __builtin_amdgcn_mfma_f32_16x16x32_f16(a[s], wfv, D[og], 0, 0, 0);
        }
    }

    // epilogue: tiled-swizzled K layout staging + contiguous 16KB dump
    const int nrow = w * 16 + quad * 4;
#pragma unroll
    for (int og = 0; og < 8; ++og) {
        const int o = og * 16 + l15;
        const float bo = bk[o];
        const int c = o >> 3, j = o & 7;
        const int sw = (c & 7) << 2;
#pragma unroll
        for (int r2 = 0; r2 < 4; ++r2) {
            const int n = nrow + r2;
            const int tl = n >> 5, m = n & 31;
            T[tl * 4096 + (c * 32 + ((m + sw) & 31)) * 8 + j] = f2h(D[og][r2] + bo);
        }
    }
    __syncthreads();
    _Float16* dstk = Ktt + ((size_t)(b * 128 + (n0 >> 5)) * 4096 + t * 32);
    const unsigned short* srck = T + t * 32;
#pragma unroll
    for (int k = 0; k < 4; ++k)
        ((int4*)dstk)[k] = ((const int4*)srck)[k];
}

// ---- flash attention + fused Q-projection prologue ----
// p fp32 [b][256][4096]; Whq fp16 prescaled log2e; bqs prescaled;
// Ktt fp16 swizzled-tiled; V bf16 [b][256][4096]; out fp32 [b][256][4096]
// LDS: one flat 76032B block; K double(8KBx2) V triple(16KBx3) P double(5KBx2)
// + Lsh; prologue staging T(17.4KB) aliases K0/K1/V0 with 2-barrier separation.
__global__ __launch_bounds__(256, 2) void flash_kernel(const float* __restrict__ Pin,
                                                       const _Float16* __restrict__ Whq,
                                                       const float* __restrict__ bqs,
                                                       const _Float16* __restrict__ Ktt,
                                                       const unsigned short* __restrict__ V,
                                                       float* __restrict__ out) {
    __shared__ __align__(16) char SH[76032];
    _Float16*       K0sh = (_Float16*)(SH);
    _Float16*       K1sh = (_Float16*)(SH + 8192);
    unsigned short* V0sh = (unsigned short*)(SH + 16384);
    unsigned short* V1sh = (unsigned short*)(SH + 32768);
    unsigned short* V2sh = (unsigned short*)(SH + 49152);
    unsigned short* P0sh = (unsigned short*)(SH + 65536);
    unsigned short* P1sh = (unsigned short*)(SH + 70656);
    float*          Lsh  = (float*)(SH + 75776);
    unsigned short* T    = (unsigned short*)SH;    // prologue staging (aliased)

    const int bx   = blockIdx.x;          // 512 = B * 64 q-tiles
    const int b    = bx >> 6;
    const int q0   = (bx & 63) << 6;
    const int t    = threadIdx.x;
    const int w    = t >> 6;
    const int lane = t & 63;
    const int l15  = lane & 15;
    const int quad = lane >> 4;
    const int q8   = quad * 8;

    const _Float16* Kb = Ktt + (size_t)b * 128 * 4096;   // 128 tiles x 4096 halfs
    const unsigned short* Vg = V + (size_t)b * CIN * NN;

    // ---- fused Q-projection: Qf computed from p directly ----
    half8 Qf[4];
    {
        half8 a[8];
        const float* Xa = Pin + ((size_t)(b * CIN + q8) * NN) + q0 + w * 16 + l15;
#pragma unroll
        for (int s = 0; s < 8; ++s) {
            const float* xs = Xa + (size_t)s * 32 * NN;
            float av[8];
#pragma unroll
            for (int j = 0; j < 8; ++j) av[j] = xs[(size_t)j * NN];
            union { half8 h; unsigned int u[4]; } af;
#pragma unroll
            for (int j = 0; j < 4; ++j) af.u[j] = pkrtz(av[2 * j], av[2 * j + 1]);
            a[s] = af.h;
        }
        f32x4 D[8];
#pragma unroll
        for (int og = 0; og < 8; ++og) D[og] = (f32x4){0.f, 0.f, 0.f, 0.f};
        const _Float16* wbase = Whq + (size_t)l15 * CIN + q8;
#pragma unroll
        for (int s = 0; s < 8; ++s) {
            const _Float16* wp = wbase + s * 32;
#pragma unroll
            for (int og = 0; og < 8; ++og) {
                half8 wfv = *(const half8*)(wp + og * 16 * CIN);
                D[og] = __builtin_amdgcn_mfma_f32_16x16x32_f16(a[s], wfv, D[og], 0, 0, 0);
            }
        }
        // stage Q^T -> [n][o] (row stride 136 halfs), transpose via LDS
        const int nrow = w * 16 + quad * 4;
#pragma unroll
        for (int og = 0; og < 8; ++og) {
            const int o = og * 16 + l15;
            const float bo = bqs[o];
#pragma unroll
            for (int r2 = 0; r2 < 4; ++r2)
                T[(nrow + r2) * 136 + o] = f2h(D[og][r2] + bo);
        }
        __syncthreads();
#pragma unroll
        for (int s = 0; s < 4; ++s)
            Qf[s] = *(const half8*)&T[(w * 16 + l15) * 136 + s * 32 + q8];
        __syncthreads();   // T dead; K/V DMA below may overwrite the region
    }

    f32x4 O[16];   // O[ni*4+cj]: n-block ni (16 n), c = w*64 + cj*16 + l15
#pragma unroll
    for (int i = 0; i < 16; ++i) O[i] = (f32x4){0.f, 0.f, 0.f, 0.f};
    float lsum[4] = {0.f, 0.f, 0.f, 0.f};

    // V DMA source remap (layout: chunk(c,mq) at position c*4 + ((mq+(c>>1))&3))
    const int vmq   = ((lane & 3) - ((lane >> 3) & 3)) & 3;   // mq this lane fetches
    const int vcrow = lane >> 2;                              // row-within-16 group
    // V read swizzle (hoisted): slot = (quad + (l15>>1)) & 3
    const int vslot = (quad + (l15 >> 1)) & 3;

    auto issueK = [&](int kt, _Float16* Kd) {
        const _Float16* gk = Kb + (size_t)kt * 4096;
        dma16(Kd + (w * 2 + 0) * 512, gk + (w * 2 + 0) * 512 + lane * 8);
        dma16(Kd + (w * 2 + 1) * 512, gk + (w * 2 + 1) * 512 + lane * 8);
    };
    auto issueV = [&](int kt, unsigned short* Vd) {
        const int k0 = kt << 5;
#pragma unroll
        for (int i = 0; i < 4; ++i) {
            const int cc = (w * 4 + i) * 16 + vcrow;
            dma16(Vd + (w * 4 + i) * 512,
                  Vg + (size_t)cc * NN + k0 + vmq * 8);
        }
    };

    // one k-tile (32 keys), single barrier:
    //   issueK(kt+1)->Kn ; S from Kc ; exp ; pack -> Pc ; BARRIER
    //   (drains K(kt+1) + V(kt+1)) ; issueV(kt+2)->Vn2 ; PV from Pc,Va
    auto halfstep = [&](int kt, const _Float16* Kc, _Float16* Kn,
                        const unsigned short* Va, unsigned short* Vn2,
                        unsigned short* Pc) {
        if (kt + 1 < 128) issueK(kt + 1, Kn);     // flies during S; drains at barrier

        // ---- S' = (Q*log2e) K^T : wave's 16 n rows x 32 m ----
        f32x4 S0 = {0.f, 0.f, 0.f, 0.f}, S1 = {0.f, 0.f, 0.f, 0.f};
        __builtin_amdgcn_s_setprio(1);
#pragma unroll
        for (int s = 0; s < 4; ++s) {
            const int kc = 4 * s + quad;          // K k-chunk (8 o's)
            const int sw = (kc & 7) << 2;
            const int x0 = (l15 + sw) & 31;
            half8 kf0 = *(const half8*)(Kc + (kc * 32 + x0) * 8);
            half8 kf1 = *(const half8*)(Kc + (kc * 32 + (x0 ^ 16)) * 8);
            S0 = __builtin_amdgcn_mfma_f32_16x16x32_f16(Qf[s], kf0, S0, 0, 0, 0);
            S1 = __builtin_amdgcn_mfma_f32_16x16x32_f16(Qf[s], kf1, S1, 0, 0, 0);
        }
        __builtin_amdgcn_s_setprio(0);

        // ---- P = 2^S' (unnormalized e^S); accumulate l ----
        f32x4 E0, E1;
#pragma unroll
        for (int r = 0; r < 4; ++r) {
            E0[r] = exp2f(S0[r]);
            E1[r] = exp2f(S1[r]);
            lsum[r] += E0[r] + E1[r];
        }
        // lane^1 exchange via DPP (VALU), pack via v_cvt_pk_bf16_f32
        {
            f32x4 P0, P1;
#pragma unroll
            for (int r = 0; r < 4; ++r) { P0[r] = dpp_xor1(E0[r]); P1[r] = dpp_xor1(E1[r]); }
            const int odd = l15 & 1;
            unsigned short* wp0 = Pc + w * 640
                                + (((quad << 2) + (odd << 1)) * 40) + (l15 & ~1);
            unsigned int pk0 = cvt_pk_bf16(odd ? P0[2] : E0[0], odd ? E0[2] : P0[0]);
            unsigned int pk1 = cvt_pk_bf16(odd ? P0[3] : E0[1], odd ? E0[3] : P0[1]);
            unsigned int pk2 = cvt_pk_bf16(odd ? P1[2] : E1[0], odd ? E1[2] : P1[0]);
            unsigned int pk3 = cvt_pk_bf16(odd ? P1[3] : E1[1], odd ? E1[3] : P1[1]);
            *(unsigned int*)&wp0[0]  = pk0;
            *(unsigned int*)&wp0[40] = pk1;
            *(unsigned int*)&wp0[16] = pk2;
            *(unsigned int*)&wp0[56] = pk3;
        }

        __syncthreads();   // P visible; K(kt+1) and V(kt+1) DMA drained

        if (kt + 2 < 128) issueV(kt + 2, Vn2);    // full halfstep of flight

        // ---- PV: wave owns c-slice w*64..+63, all 64 n ----
        {
            short8 pf[4];
#pragma unroll
            for (int ni = 0; ni < 4; ++ni)
                pf[ni] = *(const short8*)(Pc + (ni * 16 + l15) * 40 + q8);
            const unsigned short* vb = Va + (w * 64 + l15) * 32 + vslot * 8;
            __builtin_amdgcn_s_setprio(1);
#pragma unroll
            for (int cj = 0; cj < 4; ++cj) {
                short8 vf = *(const short8*)(vb + cj * 512);   // +16 c rows
#pragma unroll
                for (int ni = 0; ni < 4; ++ni)
                    O[ni * 4 + cj] = __builtin_amdgcn_mfma_f32_16x16x32_bf16(pf[ni], vf, O[ni * 4 + cj], 0, 0, 0);
            }
            __builtin_amdgcn_s_setprio(0);
        }
        // no trailing barrier: next tile's P goes to the other P buffer,
        // next K DMA targets the buffer whose readers finished pre-barrier,
        // V DMA two tiles ahead targets the slot last read before the barrier.
    };

    issueK(0, K0sh);
    issueV(0, V0sh);
    issueV(1, V1sh);
    __syncthreads();

    _Float16*       Kc = K0sh; _Float16*       Kn = K1sh;
    unsigned short* Va = V0sh; unsigned short* Vm = V1sh; unsigned short* Vn2 = V2sh;
    unsigned short* Pc = P0sh; unsigned short* Pn = P1sh;
#pragma unroll 1
    for (int kt = 0; kt < 128; ++kt) {
        halfstep(kt, Kc, Kn, Va, Vn2, Pc);
        _Float16* tk = Kc; Kc = Kn; Kn = tk;
        unsigned short* tv = Va; Va = Vm; Vm = Vn2; Vn2 = tv;
        unsigned short* tp = Pc; Pc = Pn; Pn = tp;
    }

    // ---- epilogue: row sums -> Lsh, divide, vectorized store ----
#pragma unroll
    for (int r = 0; r < 4; ++r) {
        float s = lsum[r];
        s += __shfl_xor(s, 1);
        s += __shfl_xor(s, 2);
        s += __shfl_xor(s, 4);
        s += __shfl_xor(s, 8);
        if (l15 == 0) Lsh[w * 16 + (quad << 2) + r] = s;
    }
    __syncthreads();
    float* ob = out + (size_t)b * CIN * NN + q0;
#pragma unroll
    for (int ni = 0; ni < 4; ++ni) {
        const f32x4 lv = *(const f32x4*)&Lsh[ni * 16 + (quad << 2)];
        f32x4 linv;
#pragma unroll
        for (int r = 0; r < 4; ++r) linv[r] = 1.0f / lv[r];
        const int nb = ni * 16 + (quad << 2);
#pragma unroll
        for (int cj = 0; cj < 4; ++cj) {
            const int c = w * 64 + cj * 16 + l15;
            f32x4 val = O[ni * 4 + cj];
#pragma unroll
            for (int r = 0; r < 4; ++r) val[r] *= linv[r];
            *(f32x4*)(ob + (size_t)c * NN + nb) = val;
        }
    }
}

extern "C" void kernel_launch(void* const* d_in, const int* in_sizes, int n_in,
                              void* d_out, int out_size, void* d_ws, size_t ws_size,
                              hipStream_t stream) {
    const float* p  = (const float*)d_in[0];
    const float* bv = (const float*)d_in[1];
    const float* Wq = (const float*)d_in[2];
    const float* bq = (const float*)d_in[3];
    const float* Wk = (const float*)d_in[4];
    const float* bk = (const float*)d_in[5];
    float* outp = (float*)d_out;

    char* ws = (char*)d_ws;
    const size_t szK = (size_t)B_ * NN * COUT * 2;   // 8.4 MB (fp16 tiled K)
    const size_t szV = (size_t)B_ * NN * CIN * 2;    // 16.8 MB (bf16)
    const size_t szW = (size_t)COUT * CIN * 2;       // 64 KB
    _Float16*       Ktt = (_Float16*)ws;
    unsigned short* Vb  = (unsigned short*)(ws + szK);
    _Float16*       Whq = (_Float16*)(ws + szK + szV);
    _Float16*       Whk = (_Float16*)(ws + szK + szV + szW);
    float*          bqs = (float*)(ws + szK + szV + 2 * szW);

    cvt_w<<<64, 256, 0, stream>>>(Wq, Wk, bq, Whq, Whk, bqs);
    kv_prep<<<512, 256, 0, stream>>>(bv, Whk, bk, Ktt, Vb);
    flash_kernel<<<512, 256, 0, stream>>>(p, Whq, bqs, Ktt, Vb, outp);
}